// Round 8
// baseline (300.652 us; speedup 1.0000x reference)
//
#include <hip/hip_runtime.h>

// GNNBackbone: B=4096 players, 64 asteroids each, HID=64, HEADS=4, OUT=64, L=2.
// Fully player-local; 1 block/player, both layers fused. f32 in/out, bf16 MFMA.
//
// R8: occupancy unlock via the softmax identity
//   sum_j a_j (xa_j@Wl + bl) = (sum_j a_j xa_j)@Wl + bl,
// so accT (64 VGPRs) is dead: e computed in one fused MFMA chain, messages via
// z = sum_j a_j xa[j,:] (coalesced row reads + readlane, conflict-free) then
// out = z@Wl + bl with the proven broadcast-A MFMA reusing bfr. lpb shrunk
// 17.4KB -> 4KB by a depth-2 xor{1,2} pre-reduction. LDS ~18.8KB, target 5
// blocks/CU. Barriers kept LDS-style (R7 proved chains, not barriers, are
// the cost).

typedef __bf16 bf16x8 __attribute__((ext_vector_type(8)));
typedef float  f32x4  __attribute__((ext_vector_type(4)));

union FragU { unsigned short u[8]; bf16x8 v; };

__device__ __forceinline__ float bf2f(unsigned short u) {
    union { unsigned int i; float f; } v; v.i = ((unsigned int)u) << 16; return v.f;
}
__device__ __forceinline__ unsigned short f2bf(float f) {
    union { __bf16 b; unsigned short u; } x; x.b = (__bf16)f; return x.u;
}

#define NEG_SLOPE 0.2f
#define LN_EPS 1e-5f
#define XS 88     // xa row stride in shorts (176B, 16B-aligned)

struct Smem {
    __align__(16) unsigned short xa[64 * XS];  // cols 0..63 = x, 64..70 = ea, 71 = 0
    __align__(16) unsigned short xpb[64];      // xp as bf16 (xr MFMA A-operand)
    __align__(16) unsigned short zb[256];      // per-wave z (bf16), [w*64 + k]
    __align__(16) float lpb4[4 * 64 * 4];      // per-wave [j][s] 4 partials/row
    float outp[256];
    float xp[64];
    float afs[192];
    float rbs[64], gs[64], bs[64];
};

// ws layout: wlf[65536B] | wrf[65536B] | wef[32768B] | blq[8192B] | attq[8192B] | brq[8192B]
#define WS_NEED (163840 + 3 * 8192)

__global__ __launch_bounds__(256) void prep_weights(
    const float* __restrict__ Wl, const float* __restrict__ Wr,
    const float* __restrict__ We, const float* __restrict__ bl,
    const float* __restrict__ att, const float* __restrict__ br,
    unsigned short* __restrict__ wlf, unsigned short* __restrict__ wrf,
    unsigned short* __restrict__ wef, f32x4* __restrict__ blq,
    f32x4* __restrict__ attq, f32x4* __restrict__ brq)
{
    int i = blockIdx.x * 256 + threadIdx.x;   // 128 blocks -> 32768 threads
    int jj = i & 7, t = (i >> 3) & 255, frag = (i >> 11) & 7, layer = (i >> 14) & 1;
    int nt = frag >> 1, ko = frag & 1;
    int c = (t >> 6) * 64 + nt * 16 + (t & 15);
    int kb = ko * 32 + ((t >> 4) & 3) * 8;
    wlf[i] = f2bf(Wl[layer * 16384 + (kb + jj) * 256 + c]);
    wrf[i] = f2bf(Wr[layer * 16384 + (kb + jj) * 256 + c]);
    if (i < 16384) {   // We frags, pre-zeroed for q!=0 lanes / jj==7
        int j2 = i & 7, t2 = (i >> 3) & 255, n2 = (i >> 11) & 3, l2 = (i >> 13) & 1;
        int q2 = (t2 >> 4) & 3;
        int c2 = (t2 >> 6) * 64 + n2 * 16 + (t2 & 15);
        wef[i] = (q2 == 0 && j2 < 7) ? f2bf(We[l2 * 1792 + j2 * 256 + c2])
                                     : (unsigned short)0;
    }
    if (i < 512) {     // per-thread scalar float4 tables
        int lyr = i >> 8, tt = i & 255;
        int hb = (tt >> 6) * 64, mm = tt & 15;
        f32x4 b, a, r;
        #pragma unroll
        for (int n = 0; n < 4; ++n) {
            int cc = hb + n * 16 + mm;
            b[n] = bl[lyr * 256 + cc];
            a[n] = att[lyr * 256 + cc];
            r[n] = br[lyr * 256 + cc];
        }
        blq[i] = b; attq[i] = a; brq[i] = r;
    }
}

template <bool WS>
__global__ __launch_bounds__(256, 5) void gnn_main(
    const float* __restrict__ pf, const float* __restrict__ af,
    const float* __restrict__ eat, const float* __restrict__ Wp,
    const float* __restrict__ bp, const float* __restrict__ Wa,
    const float* __restrict__ ba, const float* __restrict__ Wl,
    const float* __restrict__ bl, const float* __restrict__ Wr,
    const float* __restrict__ br, const float* __restrict__ We,
    const float* __restrict__ att, const float* __restrict__ bias,
    const float* __restrict__ lng, const float* __restrict__ lnb,
    const unsigned short* __restrict__ wlf, const unsigned short* __restrict__ wrf,
    const unsigned short* __restrict__ wef, const f32x4* __restrict__ blq,
    const f32x4* __restrict__ attq, const f32x4* __restrict__ brq,
    float* __restrict__ out)
{
    __shared__ Smem sm;
    const int p = blockIdx.x, t = threadIdx.x;
    const int w = t >> 6, l = t & 63, q = l >> 4, m = l & 15;
    const int cbase = w * 64;

    // ---------- phase 0 ----------
    if (t < 192) sm.afs[t] = af[p * 192 + t];
    if (t < 64) {
        sm.rbs[t] = fmaxf(bias[t], 0.f);
        sm.gs[t] = lng[t];
        sm.bs[t] = lnb[t];
        float acc = bp[t];
        #pragma unroll
        for (int d = 0; d < 5; ++d) acc += pf[p * 5 + d] * Wp[d * 64 + t];
        float xp0 = fmaxf(acc, 0.f);
        sm.xp[t] = xp0;
        sm.xpb[t] = f2bf(xp0);
    }
    __syncthreads();
    {
        const int k = t & 63;
        float wa0 = Wa[k], wa1 = Wa[64 + k], wa2 = Wa[128 + k], bak = ba[k];
        #pragma unroll
        for (int rep = 0; rep < 16; ++rep) {
            int j = rep * 4 + (t >> 6);
            float acc = bak + sm.afs[j * 3] * wa0 + sm.afs[j * 3 + 1] * wa1
                      + sm.afs[j * 3 + 2] * wa2;
            sm.xa[j * XS + k] = f2bf(fmaxf(acc, 0.f));
        }
    }
    #pragma unroll
    for (int idx = t; idx < 512; idx += 256) {
        int j = idx >> 3, d = idx & 7;
        sm.xa[j * XS + 64 + d] = (d < 7) ? f2bf(eat[(p * 64 + j) * 7 + d])
                                         : (unsigned short)0;
    }
    __syncthreads();

    for (int layer = 0; layer < 2; ++layer) {
        // ---------- per-thread scalars ----------
        f32x4 blv, atv, brv;
        if constexpr (WS) {
            blv = blq[layer * 256 + t];
            atv = attq[layer * 256 + t];
            brv = brq[layer * 256 + t];
        } else {
            #pragma unroll
            for (int nt = 0; nt < 4; ++nt) {
                int c = cbase + nt * 16 + m;
                blv[nt] = bl[layer * 256 + c];
                atv[nt] = att[layer * 256 + c];
                brv[nt] = br[layer * 256 + c];
            }
        }

        // ---------- xr = xp @ Wr + br via broadcast-A MFMA (registers) ----------
        float xrc[4];
        {
            FragU xf0, xf1;
            xf0.v = *reinterpret_cast<const bf16x8*>(&sm.xpb[q * 8]);
            xf1.v = *reinterpret_cast<const bf16x8*>(&sm.xpb[32 + q * 8]);
            #pragma unroll
            for (int nt = 0; nt < 4; ++nt) {
                FragU r0, r1;
                if constexpr (WS) {
                    r0.v = *reinterpret_cast<const bf16x8*>(&wrf[((layer * 8 + nt * 2 + 0) * 256 + t) * 8]);
                    r1.v = *reinterpret_cast<const bf16x8*>(&wrf[((layer * 8 + nt * 2 + 1) * 256 + t) * 8]);
                } else {
                    int c = cbase + nt * 16 + m;
                    #pragma unroll
                    for (int jj = 0; jj < 8; ++jj) {
                        r0.u[jj] = f2bf(Wr[layer * 16384 + (q * 8 + jj) * 256 + c]);
                        r1.u[jj] = f2bf(Wr[layer * 16384 + (32 + q * 8 + jj) * 256 + c]);
                    }
                }
                f32x4 cx = { brv[nt], brv[nt], brv[nt], brv[nt] };
                cx = __builtin_amdgcn_mfma_f32_16x16x32_bf16(xf0.v, r0.v, cx, 0, 0, 0);
                cx = __builtin_amdgcn_mfma_f32_16x16x32_bf16(xf1.v, r1.v, cx, 0, 0, 0);
                xrc[nt] = cx[0];
            }
        }

        // ---------- weight fragments ----------
        FragU bfr[8];
        bf16x8 ebf[4];
        if constexpr (WS) {
            #pragma unroll
            for (int f = 0; f < 8; ++f)
                bfr[f].v = *reinterpret_cast<const bf16x8*>(&wlf[((layer * 8 + f) * 256 + t) * 8]);
            #pragma unroll
            for (int nt = 0; nt < 4; ++nt)
                ebf[nt] = *reinterpret_cast<const bf16x8*>(&wef[((layer * 4 + nt) * 256 + t) * 8]);
        } else {
            const float* Wli = Wl + layer * 16384;
            #pragma unroll
            for (int nt = 0; nt < 4; ++nt) {
                int c = cbase + nt * 16 + m;
                #pragma unroll
                for (int ko = 0; ko < 2; ++ko) {
                    int kb = ko * 32 + q * 8;
                    #pragma unroll
                    for (int jj = 0; jj < 8; ++jj)
                        bfr[nt * 2 + ko].u[jj] = f2bf(Wli[(kb + jj) * 256 + c]);
                }
                FragU e;
                #pragma unroll
                for (int jj = 0; jj < 8; ++jj)
                    e.u[jj] = (q == 0 && jj < 7) ? f2bf(We[layer * 1792 + jj * 256 + c])
                                                 : (unsigned short)0;
                ebf[nt] = e.v;
            }
        }

        // ---------- fused e = xa@Wl + ea@We + bl + xr(+br); logits partials ----------
        float lp[16];
        #pragma unroll
        for (int i = 0; i < 16; ++i) lp[i] = 0.f;

        #pragma unroll
        for (int mt = 0; mt < 4; ++mt) {
            const int row = mt * 16 + m;
            bf16x8 a0 = *reinterpret_cast<const bf16x8*>(&sm.xa[row * XS + q * 8]);
            bf16x8 a1 = *reinterpret_cast<const bf16x8*>(&sm.xa[row * XS + 32 + q * 8]);
            bf16x8 a2 = *reinterpret_cast<const bf16x8*>(&sm.xa[row * XS + 64]);
            #pragma unroll
            for (int nt = 0; nt < 4; ++nt) {
                float sd = blv[nt] + xrc[nt];
                f32x4 c = { sd, sd, sd, sd };
                c = __builtin_amdgcn_mfma_f32_16x16x32_bf16(a0, bfr[nt * 2 + 0].v, c, 0, 0, 0);
                c = __builtin_amdgcn_mfma_f32_16x16x32_bf16(a1, bfr[nt * 2 + 1].v, c, 0, 0, 0);
                c = __builtin_amdgcn_mfma_f32_16x16x32_bf16(a2, ebf[nt], c, 0, 0, 0);
                #pragma unroll
                for (int r = 0; r < 4; ++r) {
                    float ev = fmaxf(c[r], NEG_SLOPE * c[r]);   // LeakyReLU
                    lp[mt * 4 + r] += ev * atv[nt];
                }
            }
        }

        // ---------- depth-2 pre-reduction over m (xor 1,2), then 4 partials/row ----------
        #pragma unroll
        for (int i = 0; i < 16; ++i) {
            float v = lp[i];
            v += __shfl_xor(v, 1, 64);
            v += __shfl_xor(v, 2, 64);
            lp[i] = v;
        }
        if ((m & 3) == 0) {
            #pragma unroll
            for (int i = 0; i < 16; ++i) {
                int j = (i >> 2) * 16 + q * 4 + (i & 3);
                sm.lpb4[(w * 64 + j) * 4 + (m >> 2)] = lp[i];
            }
        }
        __syncthreads();   // B1: partials visible

        // ---------- lane l = j: final sum + 64-lane softmax ----------
        float al;
        {
            f32x4 pr = *reinterpret_cast<const f32x4*>(&sm.lpb4[(w * 64 + l) * 4]);
            float lg = (pr[0] + pr[1]) + (pr[2] + pr[3]);
            float mx = lg;
            #pragma unroll
            for (int msk = 1; msk <= 32; msk <<= 1) mx = fmaxf(mx, __shfl_xor(mx, msk, 64));
            al = __expf(lg - mx);
            float den = al;
            #pragma unroll
            for (int msk = 1; msk <= 32; msk <<= 1) den += __shfl_xor(den, msk, 64);
            al /= den;   // alpha_j at lane j
        }

        // ---------- z = sum_j alpha_j * xa[j,:] (coalesced rows + readlane) ----------
        {
            float z0 = 0.f, z1 = 0.f, z2 = 0.f, z3 = 0.f;
            #pragma unroll
            for (int j = 0; j < 64; j += 4) {
                float s0 = __shfl(al, j, 64);
                float s1 = __shfl(al, j + 1, 64);
                float s2 = __shfl(al, j + 2, 64);
                float s3 = __shfl(al, j + 3, 64);
                z0 += s0 * bf2f(sm.xa[j * XS + l]);
                z1 += s1 * bf2f(sm.xa[(j + 1) * XS + l]);
                z2 += s2 * bf2f(sm.xa[(j + 2) * XS + l]);
                z3 += s3 * bf2f(sm.xa[(j + 3) * XS + l]);
            }
            sm.zb[w * 64 + l] = f2bf((z0 + z1) + (z2 + z3));
        }
        __syncthreads();   // B3: z visible

        // ---------- out_head = z @ Wl + bl (broadcast-A MFMA, reuses bfr) ----------
        {
            bf16x8 zf0 = *reinterpret_cast<const bf16x8*>(&sm.zb[w * 64 + q * 8]);
            bf16x8 zf1 = *reinterpret_cast<const bf16x8*>(&sm.zb[w * 64 + 32 + q * 8]);
            float oc[4];
            #pragma unroll
            for (int nt = 0; nt < 4; ++nt) {
                f32x4 c = { blv[nt], blv[nt], blv[nt], blv[nt] };
                c = __builtin_amdgcn_mfma_f32_16x16x32_bf16(zf0, bfr[nt * 2 + 0].v, c, 0, 0, 0);
                c = __builtin_amdgcn_mfma_f32_16x16x32_bf16(zf1, bfr[nt * 2 + 1].v, c, 0, 0, 0);
                oc[nt] = c[0];   // rows identical (broadcast A)
            }
            // lane (q,m) owns col q*16+m = l -> outp[t]
            float osel = (q == 0) ? oc[0] : (q == 1) ? oc[1] : (q == 2) ? oc[2] : oc[3];
            sm.outp[t] = osel;
        }
        __syncthreads();   // B4: head outputs visible

        if (layer == 0) {
            // ---------- asteroid update ----------
            {
                const int j = t >> 2, part = t & 3;
                unsigned short* rowp = &sm.xa[j * XS + part * 16];
                FragU A0, A1;
                A0.v = *reinterpret_cast<const bf16x8*>(rowp);
                A1.v = *reinterpret_cast<const bf16x8*>(rowp + 8);
                float v[16], sum = 0.f, sq = 0.f;
                #pragma unroll
                for (int i = 0; i < 16; ++i) {
                    unsigned short us = (i < 8) ? A0.u[i] : A1.u[i - 8];
                    float x = bf2f(us) + sm.rbs[part * 16 + i];
                    v[i] = x; sum += x; sq += x * x;
                }
                sum += __shfl_xor(sum, 1, 64); sq += __shfl_xor(sq, 1, 64);
                sum += __shfl_xor(sum, 2, 64); sq += __shfl_xor(sq, 2, 64);
                float mu = sum * (1.f / 64.f);
                float var = sq * (1.f / 64.f) - mu * mu;
                float rs = rsqrtf(var + LN_EPS);
                FragU O0, O1;
                #pragma unroll
                for (int i = 0; i < 16; ++i) {
                    int col = part * 16 + i;
                    unsigned short ub = f2bf((v[i] - mu) * rs * sm.gs[col] + sm.bs[col]);
                    if (i < 8) O0.u[i] = ub; else O1.u[i - 8] = ub;
                }
                *reinterpret_cast<bf16x8*>(rowp) = O0.v;
                *reinterpret_cast<bf16x8*>(rowp + 8) = O1.v;
            }
            // ---------- player update ----------
            if (t < 64) {
                float xnew = 0.25f * (sm.outp[t] + sm.outp[64 + t] + sm.outp[128 + t] + sm.outp[192 + t])
                           + bias[t];
                float v = sm.xp[t] + fmaxf(xnew, 0.f);
                float sum = v, sq = v * v;
                #pragma unroll
                for (int msk = 1; msk <= 32; msk <<= 1) {
                    sum += __shfl_xor(sum, msk, 64);
                    sq  += __shfl_xor(sq,  msk, 64);
                }
                float mu = sum * (1.f / 64.f);
                float var = sq * (1.f / 64.f) - mu * mu;
                float y = (v - mu) * rsqrtf(var + LN_EPS) * lng[t] + lnb[t];
                sm.xp[t] = y;
                sm.xpb[t] = f2bf(y);
            }
            __syncthreads();   // B5: xa/xp/xpb ready for layer 1
        } else {
            // ---------- final player update -> out ----------
            if (t < 64) {
                float xnew = 0.25f * (sm.outp[t] + sm.outp[64 + t] + sm.outp[128 + t] + sm.outp[192 + t])
                           + bias[64 + t];
                float v = sm.xp[t] + fmaxf(xnew, 0.f);
                float sum = v, sq = v * v;
                #pragma unroll
                for (int msk = 1; msk <= 32; msk <<= 1) {
                    sum += __shfl_xor(sum, msk, 64);
                    sq  += __shfl_xor(sq,  msk, 64);
                }
                float mu = sum * (1.f / 64.f);
                float var = sq * (1.f / 64.f) - mu * mu;
                float y = (v - mu) * rsqrtf(var + LN_EPS) * lng[64 + t] + lnb[64 + t];
                out[p * 64 + t] = y;
            }
        }
    }
}

extern "C" void kernel_launch(void* const* d_in, const int* in_sizes, int n_in,
                              void* d_out, int out_size, void* d_ws, size_t ws_size,
                              hipStream_t stream) {
    const float* pf   = (const float*)d_in[0];
    const float* af   = (const float*)d_in[1];
    // d_in[2] = edge_index (int32): src=arange(E), dst=src//64 — structural, unused.
    const float* eat  = (const float*)d_in[3];
    const float* Wp   = (const float*)d_in[4];
    const float* bp   = (const float*)d_in[5];
    const float* Wa   = (const float*)d_in[6];
    const float* ba   = (const float*)d_in[7];
    const float* Wl   = (const float*)d_in[8];
    const float* bl   = (const float*)d_in[9];
    const float* Wr   = (const float*)d_in[10];
    const float* br   = (const float*)d_in[11];
    const float* We   = (const float*)d_in[12];
    const float* att  = (const float*)d_in[13];
    const float* bias = (const float*)d_in[14];
    const float* lng  = (const float*)d_in[15];
    const float* lnb  = (const float*)d_in[16];
    float* out = (float*)d_out;

    const int B = in_sizes[0] / 5;  // 4096 players
    unsigned short* wlf = (unsigned short*)d_ws;   // 32768 shorts
    unsigned short* wrf = wlf + 32768;             // 32768 shorts
    unsigned short* wef = wrf + 32768;             // 16384 shorts
    f32x4* blq  = (f32x4*)((char*)d_ws + 163840);  // 512 f32x4
    f32x4* attq = blq + 512;
    f32x4* brq  = attq + 512;

    if (ws_size >= WS_NEED) {
        prep_weights<<<dim3(128), dim3(256), 0, stream>>>(
            Wl, Wr, We, bl, att, br, wlf, wrf, wef, blq, attq, brq);
        gnn_main<true><<<dim3(B), dim3(256), 0, stream>>>(
            pf, af, eat, Wp, bp, Wa, ba, Wl, bl, Wr, br, We, att, bias, lng, lnb,
            wlf, wrf, wef, blq, attq, brq, out);
    } else {
        gnn_main<false><<<dim3(B), dim3(256), 0, stream>>>(
            pf, af, eat, Wp, bp, Wa, ba, Wl, bl, Wr, br, We, att, bias, lng, lnb,
            wlf, wrf, wef, blq, attq, brq, out);
    }
}

// Round 9
// 181.518 us; speedup vs baseline: 1.6563x; 1.6563x over previous
//
#include <hip/hip_runtime.h>

// GNNBackbone: B=4096 players, 64 asteroids each, HID=64, HEADS=4, OUT=64, L=2.
// Fully player-local; 1 block/player, both layers fused. f32 in/out, bf16 MFMA.
//
// R9: R8's structure (accT eliminated via sum_j a_j (xa@Wl+bl) = (sum_j a_j xa)@Wl+bl,
// 4KB lp buffer, z row-sum, broadcast-A output MFMA) WITHOUT the forced
// __launch_bounds__(256,5): R8's counters showed VGPR crushed to 48 with 715MB
// of scratch spill traffic (FETCH 244MB / WRITE 471MB). Natural allocation
// (~96-128 VGPR) + 18.9KB LDS gives better residency than R6 with zero spill.

typedef __bf16 bf16x8 __attribute__((ext_vector_type(8)));
typedef float  f32x4  __attribute__((ext_vector_type(4)));

union FragU { unsigned short u[8]; bf16x8 v; };

__device__ __forceinline__ float bf2f(unsigned short u) {
    union { unsigned int i; float f; } v; v.i = ((unsigned int)u) << 16; return v.f;
}
__device__ __forceinline__ unsigned short f2bf(float f) {
    union { __bf16 b; unsigned short u; } x; x.b = (__bf16)f; return x.u;
}

#define NEG_SLOPE 0.2f
#define LN_EPS 1e-5f
#define XS 88     // xa row stride in shorts (176B, 16B-aligned)

struct Smem {
    __align__(16) unsigned short xa[64 * XS];  // cols 0..63 = x, 64..70 = ea, 71 = 0
    __align__(16) unsigned short xpb[64];      // xp as bf16 (xr MFMA A-operand)
    __align__(16) unsigned short zb[256];      // per-wave z (bf16), [w*64 + k]
    __align__(16) float lpb4[4 * 64 * 4];      // per-wave [j][s] 4 partials/row
    float outp[256];
    float xp[64];
    float afs[192];
    float rbs[64], gs[64], bs[64];
};

// ws layout: wlf[65536B] | wrf[65536B] | wef[32768B] | blq[8192B] | attq[8192B] | brq[8192B]
#define WS_NEED (163840 + 3 * 8192)

__global__ __launch_bounds__(256) void prep_weights(
    const float* __restrict__ Wl, const float* __restrict__ Wr,
    const float* __restrict__ We, const float* __restrict__ bl,
    const float* __restrict__ att, const float* __restrict__ br,
    unsigned short* __restrict__ wlf, unsigned short* __restrict__ wrf,
    unsigned short* __restrict__ wef, f32x4* __restrict__ blq,
    f32x4* __restrict__ attq, f32x4* __restrict__ brq)
{
    int i = blockIdx.x * 256 + threadIdx.x;   // 128 blocks -> 32768 threads
    int jj = i & 7, t = (i >> 3) & 255, frag = (i >> 11) & 7, layer = (i >> 14) & 1;
    int nt = frag >> 1, ko = frag & 1;
    int c = (t >> 6) * 64 + nt * 16 + (t & 15);
    int kb = ko * 32 + ((t >> 4) & 3) * 8;
    wlf[i] = f2bf(Wl[layer * 16384 + (kb + jj) * 256 + c]);
    wrf[i] = f2bf(Wr[layer * 16384 + (kb + jj) * 256 + c]);
    if (i < 16384) {   // We frags, pre-zeroed for q!=0 lanes / jj==7
        int j2 = i & 7, t2 = (i >> 3) & 255, n2 = (i >> 11) & 3, l2 = (i >> 13) & 1;
        int q2 = (t2 >> 4) & 3;
        int c2 = (t2 >> 6) * 64 + n2 * 16 + (t2 & 15);
        wef[i] = (q2 == 0 && j2 < 7) ? f2bf(We[l2 * 1792 + j2 * 256 + c2])
                                     : (unsigned short)0;
    }
    if (i < 512) {     // per-thread scalar float4 tables
        int lyr = i >> 8, tt = i & 255;
        int hb = (tt >> 6) * 64, mm = tt & 15;
        f32x4 b, a, r;
        #pragma unroll
        for (int n = 0; n < 4; ++n) {
            int cc = hb + n * 16 + mm;
            b[n] = bl[lyr * 256 + cc];
            a[n] = att[lyr * 256 + cc];
            r[n] = br[lyr * 256 + cc];
        }
        blq[i] = b; attq[i] = a; brq[i] = r;
    }
}

template <bool WS>
__global__ __launch_bounds__(256) void gnn_main(
    const float* __restrict__ pf, const float* __restrict__ af,
    const float* __restrict__ eat, const float* __restrict__ Wp,
    const float* __restrict__ bp, const float* __restrict__ Wa,
    const float* __restrict__ ba, const float* __restrict__ Wl,
    const float* __restrict__ bl, const float* __restrict__ Wr,
    const float* __restrict__ br, const float* __restrict__ We,
    const float* __restrict__ att, const float* __restrict__ bias,
    const float* __restrict__ lng, const float* __restrict__ lnb,
    const unsigned short* __restrict__ wlf, const unsigned short* __restrict__ wrf,
    const unsigned short* __restrict__ wef, const f32x4* __restrict__ blq,
    const f32x4* __restrict__ attq, const f32x4* __restrict__ brq,
    float* __restrict__ out)
{
    __shared__ Smem sm;
    const int p = blockIdx.x, t = threadIdx.x;
    const int w = t >> 6, l = t & 63, q = l >> 4, m = l & 15;
    const int cbase = w * 64;

    // ---------- phase 0 ----------
    if (t < 192) sm.afs[t] = af[p * 192 + t];
    if (t < 64) {
        sm.rbs[t] = fmaxf(bias[t], 0.f);
        sm.gs[t] = lng[t];
        sm.bs[t] = lnb[t];
        float acc = bp[t];
        #pragma unroll
        for (int d = 0; d < 5; ++d) acc += pf[p * 5 + d] * Wp[d * 64 + t];
        float xp0 = fmaxf(acc, 0.f);
        sm.xp[t] = xp0;
        sm.xpb[t] = f2bf(xp0);
    }
    __syncthreads();
    {
        const int k = t & 63;
        float wa0 = Wa[k], wa1 = Wa[64 + k], wa2 = Wa[128 + k], bak = ba[k];
        #pragma unroll
        for (int rep = 0; rep < 16; ++rep) {
            int j = rep * 4 + (t >> 6);
            float acc = bak + sm.afs[j * 3] * wa0 + sm.afs[j * 3 + 1] * wa1
                      + sm.afs[j * 3 + 2] * wa2;
            sm.xa[j * XS + k] = f2bf(fmaxf(acc, 0.f));
        }
    }
    #pragma unroll
    for (int idx = t; idx < 512; idx += 256) {
        int j = idx >> 3, d = idx & 7;
        sm.xa[j * XS + 64 + d] = (d < 7) ? f2bf(eat[(p * 64 + j) * 7 + d])
                                         : (unsigned short)0;
    }
    __syncthreads();

    for (int layer = 0; layer < 2; ++layer) {
        // ---------- per-thread scalars ----------
        f32x4 blv, atv, brv;
        if constexpr (WS) {
            blv = blq[layer * 256 + t];
            atv = attq[layer * 256 + t];
            brv = brq[layer * 256 + t];
        } else {
            #pragma unroll
            for (int nt = 0; nt < 4; ++nt) {
                int c = cbase + nt * 16 + m;
                blv[nt] = bl[layer * 256 + c];
                atv[nt] = att[layer * 256 + c];
                brv[nt] = br[layer * 256 + c];
            }
        }

        // ---------- xr = xp @ Wr + br via broadcast-A MFMA (registers) ----------
        float xrc[4];
        {
            FragU xf0, xf1;
            xf0.v = *reinterpret_cast<const bf16x8*>(&sm.xpb[q * 8]);
            xf1.v = *reinterpret_cast<const bf16x8*>(&sm.xpb[32 + q * 8]);
            #pragma unroll
            for (int nt = 0; nt < 4; ++nt) {
                FragU r0, r1;
                if constexpr (WS) {
                    r0.v = *reinterpret_cast<const bf16x8*>(&wrf[((layer * 8 + nt * 2 + 0) * 256 + t) * 8]);
                    r1.v = *reinterpret_cast<const bf16x8*>(&wrf[((layer * 8 + nt * 2 + 1) * 256 + t) * 8]);
                } else {
                    int c = cbase + nt * 16 + m;
                    #pragma unroll
                    for (int jj = 0; jj < 8; ++jj) {
                        r0.u[jj] = f2bf(Wr[layer * 16384 + (q * 8 + jj) * 256 + c]);
                        r1.u[jj] = f2bf(Wr[layer * 16384 + (32 + q * 8 + jj) * 256 + c]);
                    }
                }
                f32x4 cx = { brv[nt], brv[nt], brv[nt], brv[nt] };
                cx = __builtin_amdgcn_mfma_f32_16x16x32_bf16(xf0.v, r0.v, cx, 0, 0, 0);
                cx = __builtin_amdgcn_mfma_f32_16x16x32_bf16(xf1.v, r1.v, cx, 0, 0, 0);
                xrc[nt] = cx[0];
            }
        }

        // ---------- weight fragments ----------
        FragU bfr[8];
        bf16x8 ebf[4];
        if constexpr (WS) {
            #pragma unroll
            for (int f = 0; f < 8; ++f)
                bfr[f].v = *reinterpret_cast<const bf16x8*>(&wlf[((layer * 8 + f) * 256 + t) * 8]);
            #pragma unroll
            for (int nt = 0; nt < 4; ++nt)
                ebf[nt] = *reinterpret_cast<const bf16x8*>(&wef[((layer * 4 + nt) * 256 + t) * 8]);
        } else {
            const float* Wli = Wl + layer * 16384;
            #pragma unroll
            for (int nt = 0; nt < 4; ++nt) {
                int c = cbase + nt * 16 + m;
                #pragma unroll
                for (int ko = 0; ko < 2; ++ko) {
                    int kb = ko * 32 + q * 8;
                    #pragma unroll
                    for (int jj = 0; jj < 8; ++jj)
                        bfr[nt * 2 + ko].u[jj] = f2bf(Wli[(kb + jj) * 256 + c]);
                }
                FragU e;
                #pragma unroll
                for (int jj = 0; jj < 8; ++jj)
                    e.u[jj] = (q == 0 && jj < 7) ? f2bf(We[layer * 1792 + jj * 256 + c])
                                                 : (unsigned short)0;
                ebf[nt] = e.v;
            }
        }

        // ---------- fused e = xa@Wl + ea@We + bl + xr(+br); logits partials ----------
        float lp[16];
        #pragma unroll
        for (int i = 0; i < 16; ++i) lp[i] = 0.f;

        #pragma unroll
        for (int mt = 0; mt < 4; ++mt) {
            const int row = mt * 16 + m;
            bf16x8 a0 = *reinterpret_cast<const bf16x8*>(&sm.xa[row * XS + q * 8]);
            bf16x8 a1 = *reinterpret_cast<const bf16x8*>(&sm.xa[row * XS + 32 + q * 8]);
            bf16x8 a2 = *reinterpret_cast<const bf16x8*>(&sm.xa[row * XS + 64]);
            #pragma unroll
            for (int nt = 0; nt < 4; ++nt) {
                float sd = blv[nt] + xrc[nt];
                f32x4 c = { sd, sd, sd, sd };
                c = __builtin_amdgcn_mfma_f32_16x16x32_bf16(a0, bfr[nt * 2 + 0].v, c, 0, 0, 0);
                c = __builtin_amdgcn_mfma_f32_16x16x32_bf16(a1, bfr[nt * 2 + 1].v, c, 0, 0, 0);
                c = __builtin_amdgcn_mfma_f32_16x16x32_bf16(a2, ebf[nt], c, 0, 0, 0);
                #pragma unroll
                for (int r = 0; r < 4; ++r) {
                    float ev = fmaxf(c[r], NEG_SLOPE * c[r]);   // LeakyReLU
                    lp[mt * 4 + r] += ev * atv[nt];
                }
            }
        }

        // ---------- depth-2 pre-reduction over m (xor 1,2), then 4 partials/row ----------
        #pragma unroll
        for (int i = 0; i < 16; ++i) {
            float v = lp[i];
            v += __shfl_xor(v, 1, 64);
            v += __shfl_xor(v, 2, 64);
            lp[i] = v;
        }
        if ((m & 3) == 0) {
            #pragma unroll
            for (int i = 0; i < 16; ++i) {
                int j = (i >> 2) * 16 + q * 4 + (i & 3);
                sm.lpb4[(w * 64 + j) * 4 + (m >> 2)] = lp[i];
            }
        }
        __syncthreads();   // B1: partials visible

        // ---------- lane l = j: final sum + 64-lane softmax ----------
        float al;
        {
            f32x4 pr = *reinterpret_cast<const f32x4*>(&sm.lpb4[(w * 64 + l) * 4]);
            float lg = (pr[0] + pr[1]) + (pr[2] + pr[3]);
            float mx = lg;
            #pragma unroll
            for (int msk = 1; msk <= 32; msk <<= 1) mx = fmaxf(mx, __shfl_xor(mx, msk, 64));
            al = __expf(lg - mx);
            float den = al;
            #pragma unroll
            for (int msk = 1; msk <= 32; msk <<= 1) den += __shfl_xor(den, msk, 64);
            al /= den;   // alpha_j at lane j
        }

        // ---------- z = sum_j alpha_j * xa[j,:] (coalesced rows + readlane) ----------
        {
            float z0 = 0.f, z1 = 0.f, z2 = 0.f, z3 = 0.f;
            #pragma unroll
            for (int j = 0; j < 64; j += 4) {
                float s0 = __shfl(al, j, 64);
                float s1 = __shfl(al, j + 1, 64);
                float s2 = __shfl(al, j + 2, 64);
                float s3 = __shfl(al, j + 3, 64);
                z0 += s0 * bf2f(sm.xa[j * XS + l]);
                z1 += s1 * bf2f(sm.xa[(j + 1) * XS + l]);
                z2 += s2 * bf2f(sm.xa[(j + 2) * XS + l]);
                z3 += s3 * bf2f(sm.xa[(j + 3) * XS + l]);
            }
            sm.zb[w * 64 + l] = f2bf((z0 + z1) + (z2 + z3));
        }
        __syncthreads();   // B2: z visible

        // ---------- out_head = z @ Wl + bl (broadcast-A MFMA, reuses bfr) ----------
        {
            bf16x8 zf0 = *reinterpret_cast<const bf16x8*>(&sm.zb[w * 64 + q * 8]);
            bf16x8 zf1 = *reinterpret_cast<const bf16x8*>(&sm.zb[w * 64 + 32 + q * 8]);
            float oc[4];
            #pragma unroll
            for (int nt = 0; nt < 4; ++nt) {
                f32x4 c = { blv[nt], blv[nt], blv[nt], blv[nt] };
                c = __builtin_amdgcn_mfma_f32_16x16x32_bf16(zf0, bfr[nt * 2 + 0].v, c, 0, 0, 0);
                c = __builtin_amdgcn_mfma_f32_16x16x32_bf16(zf1, bfr[nt * 2 + 1].v, c, 0, 0, 0);
                oc[nt] = c[0];   // rows identical (broadcast A)
            }
            // lane (q,m) owns col q*16+m = l -> outp[t]
            float osel = (q == 0) ? oc[0] : (q == 1) ? oc[1] : (q == 2) ? oc[2] : oc[3];
            sm.outp[t] = osel;
        }
        __syncthreads();   // B3: head outputs visible

        if (layer == 0) {
            // ---------- asteroid update ----------
            {
                const int j = t >> 2, part = t & 3;
                unsigned short* rowp = &sm.xa[j * XS + part * 16];
                FragU A0, A1;
                A0.v = *reinterpret_cast<const bf16x8*>(rowp);
                A1.v = *reinterpret_cast<const bf16x8*>(rowp + 8);
                float v[16], sum = 0.f, sq = 0.f;
                #pragma unroll
                for (int i = 0; i < 16; ++i) {
                    unsigned short us = (i < 8) ? A0.u[i] : A1.u[i - 8];
                    float x = bf2f(us) + sm.rbs[part * 16 + i];
                    v[i] = x; sum += x; sq += x * x;
                }
                sum += __shfl_xor(sum, 1, 64); sq += __shfl_xor(sq, 1, 64);
                sum += __shfl_xor(sum, 2, 64); sq += __shfl_xor(sq, 2, 64);
                float mu = sum * (1.f / 64.f);
                float var = sq * (1.f / 64.f) - mu * mu;
                float rs = rsqrtf(var + LN_EPS);
                FragU O0, O1;
                #pragma unroll
                for (int i = 0; i < 16; ++i) {
                    int col = part * 16 + i;
                    unsigned short ub = f2bf((v[i] - mu) * rs * sm.gs[col] + sm.bs[col]);
                    if (i < 8) O0.u[i] = ub; else O1.u[i - 8] = ub;
                }
                *reinterpret_cast<bf16x8*>(rowp) = O0.v;
                *reinterpret_cast<bf16x8*>(rowp + 8) = O1.v;
            }
            // ---------- player update ----------
            if (t < 64) {
                float xnew = 0.25f * (sm.outp[t] + sm.outp[64 + t] + sm.outp[128 + t] + sm.outp[192 + t])
                           + bias[t];
                float v = sm.xp[t] + fmaxf(xnew, 0.f);
                float sum = v, sq = v * v;
                #pragma unroll
                for (int msk = 1; msk <= 32; msk <<= 1) {
                    sum += __shfl_xor(sum, msk, 64);
                    sq  += __shfl_xor(sq,  msk, 64);
                }
                float mu = sum * (1.f / 64.f);
                float var = sq * (1.f / 64.f) - mu * mu;
                float y = (v - mu) * rsqrtf(var + LN_EPS) * lng[t] + lnb[t];
                sm.xp[t] = y;
                sm.xpb[t] = f2bf(y);
            }
            __syncthreads();   // B4: xa/xp/xpb ready for layer 1
        } else {
            // ---------- final player update -> out ----------
            if (t < 64) {
                float xnew = 0.25f * (sm.outp[t] + sm.outp[64 + t] + sm.outp[128 + t] + sm.outp[192 + t])
                           + bias[64 + t];
                float v = sm.xp[t] + fmaxf(xnew, 0.f);
                float sum = v, sq = v * v;
                #pragma unroll
                for (int msk = 1; msk <= 32; msk <<= 1) {
                    sum += __shfl_xor(sum, msk, 64);
                    sq  += __shfl_xor(sq,  msk, 64);
                }
                float mu = sum * (1.f / 64.f);
                float var = sq * (1.f / 64.f) - mu * mu;
                float y = (v - mu) * rsqrtf(var + LN_EPS) * lng[64 + t] + lnb[64 + t];
                out[p * 64 + t] = y;
            }
        }
    }
}

extern "C" void kernel_launch(void* const* d_in, const int* in_sizes, int n_in,
                              void* d_out, int out_size, void* d_ws, size_t ws_size,
                              hipStream_t stream) {
    const float* pf   = (const float*)d_in[0];
    const float* af   = (const float*)d_in[1];
    // d_in[2] = edge_index (int32): src=arange(E), dst=src//64 — structural, unused.
    const float* eat  = (const float*)d_in[3];
    const float* Wp   = (const float*)d_in[4];
    const float* bp   = (const float*)d_in[5];
    const float* Wa   = (const float*)d_in[6];
    const float* ba   = (const float*)d_in[7];
    const float* Wl   = (const float*)d_in[8];
    const float* bl   = (const float*)d_in[9];
    const float* Wr   = (const float*)d_in[10];
    const float* br   = (const float*)d_in[11];
    const float* We   = (const float*)d_in[12];
    const float* att  = (const float*)d_in[13];
    const float* bias = (const float*)d_in[14];
    const float* lng  = (const float*)d_in[15];
    const float* lnb  = (const float*)d_in[16];
    float* out = (float*)d_out;

    const int B = in_sizes[0] / 5;  // 4096 players
    unsigned short* wlf = (unsigned short*)d_ws;   // 32768 shorts
    unsigned short* wrf = wlf + 32768;             // 32768 shorts
    unsigned short* wef = wrf + 32768;             // 16384 shorts
    f32x4* blq  = (f32x4*)((char*)d_ws + 163840);  // 512 f32x4
    f32x4* attq = blq + 512;
    f32x4* brq  = attq + 512;

    if (ws_size >= WS_NEED) {
        prep_weights<<<dim3(128), dim3(256), 0, stream>>>(
            Wl, Wr, We, bl, att, br, wlf, wrf, wef, blq, attq, brq);
        gnn_main<true><<<dim3(B), dim3(256), 0, stream>>>(
            pf, af, eat, Wp, bp, Wa, ba, Wl, bl, Wr, br, We, att, bias, lng, lnb,
            wlf, wrf, wef, blq, attq, brq, out);
    } else {
        gnn_main<false><<<dim3(B), dim3(256), 0, stream>>>(
            pf, af, eat, Wp, bp, Wa, ba, Wl, bl, Wr, br, We, att, bias, lng, lnb,
            wlf, wrf, wef, blq, attq, brq, out);
    }
}